// Round 12
// baseline (164.071 us; speedup 1.0000x reference)
//
#include <hip/hip_runtime.h>
#include <hip/hip_fp16.h>
#include <math.h>

#define SEQ   4096
#define DIM   128
#define UDIM  64
#define BATCH 4
#define BS    (BATCH*SEQ)

typedef _Float16 h8 __attribute__((ext_vector_type(8)));
typedef _Float16 h4 __attribute__((ext_vector_type(4)));
typedef _Float16 h2 __attribute__((ext_vector_type(2)));
typedef float    f4 __attribute__((ext_vector_type(4)));

#define MFMA_K32(a,b,c) __builtin_amdgcn_mfma_f32_16x16x32_f16((a),(b),(c),0,0,0)
#define MFMA_K16(a,b,c) __builtin_amdgcn_mfma_f32_16x16x16f16((a),(b),(c),0,0,0)

__device__ __forceinline__ h2 pk2(float a, float b) {
  return __builtin_bit_cast(h2, __builtin_amdgcn_cvt_pkrtz(a, b));
}
__device__ __forceinline__ float fexp2(float x) {
#if __has_builtin(__builtin_amdgcn_exp2f)
  return __builtin_amdgcn_exp2f(x);
#else
  return exp2f(x);
#endif
}

#define WT_STRIDE 272   // W^T row stride (136 halves): conflict-free b128
#define KB_STRIDE 144
#define L2E 1.44269504088896f

// Swizzled layouts, contiguous 8KB per 64-key tile (immediate-offset loads):
//  kswz: [kb][ks][lane] h8 : lane(quad,n) holds K[kb*16+n][ks*32+quad*8..+7]
//  vswz: [kb][pr][lane] h8 : low h4 = V^T[(2pr)*16+n][kb*16+quad*4..+3],
//                            high h4 = V^T[(2pr+1)*16+n][...]
// q is stored PRE-SCALED by log2(e) -> scores emerge in log2 domain.

// ---------------- Kernel A: FUSED qkv projection via MFMA ----------------
__global__ __launch_bounds__(256, 2) void proj_mfma(
    const float* __restrict__ x,
    const float* __restrict__ Wq, const float* __restrict__ bq,
    const float* __restrict__ Wk, const float* __restrict__ bk,
    const float* __restrict__ Wv, const float* __restrict__ bv,
    _Float16* __restrict__ qf, _Float16* __restrict__ kswz, _Float16* __restrict__ vswz)
{
  const int tid  = threadIdx.x;
  const int lane = tid & 63, wv = tid >> 6;
  const int n = lane & 15, quad = lane >> 4;
  const int r0 = blockIdx.x * 64;

  __shared__ __align__(16) char wlds[3][UDIM * WT_STRIDE];   // 52224 B
  __shared__ __align__(16) char kbnc[4 * 16 * KB_STRIDE];    //  9216 B

  #pragma unroll
  for (int p = 0; p < 3; ++p) {
    const float* __restrict__ W = (p == 0) ? Wq : ((p == 1) ? Wk : Wv);
    #pragma unroll
    for (int i = 0; i < 8; ++i) {
      const int idx = i*256 + tid;
      const int nn  = idx & 63;
      const int k4  = (idx >> 6) * 4;
      const float w0 = W[(k4+0)*UDIM + nn];
      const float w1 = W[(k4+1)*UDIM + nn];
      const float w2 = W[(k4+2)*UDIM + nn];
      const float w3 = W[(k4+3)*UDIM + nn];
      int2 wd;
      wd.x = __builtin_bit_cast(int, pk2(w0, w1));
      wd.y = __builtin_bit_cast(int, pk2(w2, w3));
      *(int2*)(wlds[p] + nn*WT_STRIDE + k4*2) = wd;
    }
  }

  const int row = r0 + wv*16 + n;
  h8 xa[4];
  #pragma unroll
  for (int ks = 0; ks < 4; ++ks) {
    const float* xp = x + (size_t)row*DIM + ks*32 + quad*8;
    const f4 a = *(const f4*)xp, b = *(const f4*)(xp + 4);
    int4 pkd;
    pkd.x = __builtin_bit_cast(int, pk2(a[0], a[1]));
    pkd.y = __builtin_bit_cast(int, pk2(a[2], a[3]));
    pkd.z = __builtin_bit_cast(int, pk2(b[0], b[1]));
    pkd.w = __builtin_bit_cast(int, pk2(b[2], b[3]));
    xa[ks] = __builtin_bit_cast(h8, pkd);
  }
  __syncthreads();

  const int b  = r0 / SEQ;
  const int kb = ((r0 % SEQ) >> 4) + wv;

  #pragma unroll
  for (int p = 0; p < 3; ++p) {
    const float* __restrict__ bias = (p == 0) ? bq : ((p == 1) ? bk : bv);
    f4 acc[4];
    #pragma unroll
    for (int nt = 0; nt < 4; ++nt) acc[nt] = (f4){0.f,0.f,0.f,0.f};
    #pragma unroll
    for (int ks = 0; ks < 4; ++ks)
      #pragma unroll
      for (int nt = 0; nt < 4; ++nt) {
        const h8 wf = *(const h8*)(wlds[p] + (nt*16 + n)*WT_STRIDE + (ks*32 + quad*8)*2);
        acc[nt] = MFMA_K32(xa[ks], wf, acc[nt]);
      }
    #pragma unroll
    for (int nt = 0; nt < 4; ++nt) {
      const float bb = bias[nt*16 + n];
      #pragma unroll
      for (int r = 0; r < 4; ++r) acc[nt][r] += bb;
    }

    if (p == 0) {
      #pragma unroll
      for (int nt = 0; nt < 4; ++nt)
        #pragma unroll
        for (int r = 0; r < 4; ++r) acc[nt][r] *= L2E;
      const int par = lane & 1;
      const unsigned sel = par ? 0x03020706u : 0x05040100u;
      #pragma unroll
      for (int nt = 0; nt < 4; ++nt)
        #pragma unroll
        for (int pp = 0; pp < 2; ++pp) {
          const int r = 2*pp;
          unsigned A  = __builtin_bit_cast(unsigned, pk2(acc[nt][r], acc[nt][r+1]));
          unsigned Bs = (unsigned)__builtin_amdgcn_mov_dpp((int)A, 0xB1, 0xF, 0xF, true);
          unsigned w  = __builtin_amdgcn_perm(Bs, A, sel);
          const int orow = r0 + wv*16 + 4*quad + r + par;
          const int ocol = nt*16 + n - par;
          *(unsigned*)((char*)qf + ((size_t)orow*UDIM + ocol)*2) = w;
        }
    } else if (p == 1) {
      char* base = kbnc + wv*(16*KB_STRIDE);
      #pragma unroll
      for (int nt = 0; nt < 4; ++nt)
        #pragma unroll
        for (int r = 0; r < 4; ++r)
          *(_Float16*)(base + (4*quad + r)*KB_STRIDE + (nt*16 + n)*2) =
              (_Float16)acc[nt][r];
      _Float16* kdst = kswz + (size_t)b*SEQ*UDIM;
      #pragma unroll
      for (int ks = 0; ks < 2; ++ks) {
        const h8 f = *(const h8*)(base + n*KB_STRIDE + ks*64 + quad*16);
        *(h8*)(kdst + ((size_t)(kb*2 + ks)*64 + lane)*8) = f;
      }
    } else {
      _Float16* vdst = vswz + (size_t)b*SEQ*UDIM;
      #pragma unroll
      for (int pr = 0; pr < 2; ++pr) {
        int4 t;
        t.x = __builtin_bit_cast(int, pk2(acc[2*pr][0],   acc[2*pr][1]));
        t.y = __builtin_bit_cast(int, pk2(acc[2*pr][2],   acc[2*pr][3]));
        t.z = __builtin_bit_cast(int, pk2(acc[2*pr+1][0], acc[2*pr+1][1]));
        t.w = __builtin_bit_cast(int, pk2(acc[2*pr+1][2], acc[2*pr+1][3]));
        *(int4*)(vdst + ((size_t)(kb*2 + pr)*64 + lane)*8) = t;
      }
    }
  }
}

// ---------------- Kernel B: barrier-free flash (R10 pipeline, 4 w/SIMD) --
// K prefetched one tile ahead in place; V one keyblock ahead. launch_bounds
// (256,4): peak live ~126 regs fits 128 -> 16 waves/CU.
__global__ __launch_bounds__(256, 4) void flash_attn_t(
    const _Float16* __restrict__ qf, const _Float16* __restrict__ kswz,
    const _Float16* __restrict__ vswz,
    _Float16* __restrict__ opart, float* __restrict__ Mp, float* __restrict__ Lp,
    int nkt)
{
  const int qt = blockIdx.x, b = blockIdx.y, sp = blockIdx.z;
  const int tid = threadIdx.x;
  const int lane = tid & 63, wid = tid >> 6;
  const int n = lane & 15, quad = lane >> 4;
  const int qbase = qt*128 + wid*32;

  const _Float16* __restrict__ qb = qf + (size_t)b*SEQ*UDIM;
  const _Float16* kpl = kswz + (size_t)b*SEQ*UDIM + (size_t)sp*nkt*4096 + lane*8;
  const _Float16* kph = kpl + 2048;
  const _Float16* vpl = vswz + (size_t)b*SEQ*UDIM + (size_t)sp*nkt*4096 + lane*8;
  const _Float16* vph = vpl + 2048;

  h8 qB[2][2];
  #pragma unroll
  for (int nt = 0; nt < 2; ++nt)
    #pragma unroll
    for (int ks = 0; ks < 2; ++ks)
      qB[nt][ks] = *(const h8*)(qb + (size_t)(qbase + nt*16 + n)*UDIM + ks*32 + quad*8);

  f4 O[4][2], Ol[2];
  #pragma unroll
  for (int ut = 0; ut < 4; ++ut)
    #pragma unroll
    for (int nt = 0; nt < 2; ++nt) O[ut][nt] = (f4){0.f,0.f,0.f,0.f};
  Ol[0] = (f4){0.f,0.f,0.f,0.f};
  Ol[1] = (f4){0.f,0.f,0.f,0.f};

  float M[2] = {-1e30f, -1e30f};

  h4 ones_a;
  { const _Float16 o = (_Float16)1.0f;
    ones_a[0]=o; ones_a[1]=o; ones_a[2]=o; ones_a[3]=o; }

  // ---- prime K for tile 0 ----
  h8 ka[4][2];
  ka[0][0] = *(const h8*)(kpl);        ka[0][1] = *(const h8*)(kpl +  512);
  ka[1][0] = *(const h8*)(kpl + 1024); ka[1][1] = *(const h8*)(kpl + 1536);
  ka[2][0] = *(const h8*)(kph);        ka[2][1] = *(const h8*)(kph +  512);
  ka[3][0] = *(const h8*)(kph + 1024); ka[3][1] = *(const h8*)(kph + 1536);

  for (int t = 0; t < nkt; ++t) {
    // ---- V keyblock 0 loads: issue now, consumed after softmax ----
    h8 vc0 = *(const h8*)(vpl);
    h8 vc1 = *(const h8*)(vpl + 512);

    // ---- S^T = K·Q^T (log2 domain: q pre-scaled) ----
    f4 S[4][2];
    #pragma unroll
    for (int mt = 0; mt < 4; ++mt)
      #pragma unroll
      for (int nt = 0; nt < 2; ++nt) S[mt][nt] = (f4){0.f,0.f,0.f,0.f};
    #pragma unroll
    for (int ks = 0; ks < 2; ++ks)
      #pragma unroll
      for (int mt = 0; mt < 4; ++mt)
        #pragma unroll
        for (int nt = 0; nt < 2; ++nt)
          S[mt][nt] = MFMA_K32(ka[mt][ks], qB[nt][ks], S[mt][nt]);

    // ---- prefetch tile t+1's K in place (consumed next iter) ----
    if (t + 1 < nkt) {
      kpl += 4096; kph += 4096;
      ka[0][0] = *(const h8*)(kpl);        ka[0][1] = *(const h8*)(kpl +  512);
      ka[1][0] = *(const h8*)(kpl + 1024); ka[1][1] = *(const h8*)(kpl + 1536);
      ka[2][0] = *(const h8*)(kph);        ka[2][1] = *(const h8*)(kph +  512);
      ka[3][0] = *(const h8*)(kph + 1024); ka[3][1] = *(const h8*)(kph + 1536);
    }

    // ---- row max: tree + 2 shuffles ----
    float mn[2];
    #pragma unroll
    for (int nt = 0; nt < 2; ++nt) {
      float m0 = fmaxf(fmaxf(S[0][nt][0], S[0][nt][1]), fmaxf(S[0][nt][2], S[0][nt][3]));
      float m1 = fmaxf(fmaxf(S[1][nt][0], S[1][nt][1]), fmaxf(S[1][nt][2], S[1][nt][3]));
      float m2 = fmaxf(fmaxf(S[2][nt][0], S[2][nt][1]), fmaxf(S[2][nt][2], S[2][nt][3]));
      float m3 = fmaxf(fmaxf(S[3][nt][0], S[3][nt][1]), fmaxf(S[3][nt][2], S[3][nt][3]));
      float rm = fmaxf(fmaxf(m0, m1), fmaxf(m2, m3));
      rm = fmaxf(rm, __shfl_xor(rm, 16));
      rm = fmaxf(rm, __shfl_xor(rm, 32));
      mn[nt] = fmaxf(M[nt], rm);
    }

    // ---- rescale O only if some lane's max moved ----
    const bool nochange = (mn[0] == M[0]) && (mn[1] == M[1]);
    if (!__all(nochange)) {
      #pragma unroll
      for (int nt = 0; nt < 2; ++nt) {
        const float alpha = fexp2(M[nt] - mn[nt]);
        #pragma unroll
        for (int ut = 0; ut < 4; ++ut)
          #pragma unroll
          for (int r = 0; r < 4; ++r) O[ut][nt][r] *= alpha;
        #pragma unroll
        for (int r = 0; r < 4; ++r) Ol[nt][r] *= alpha;
      }
    }
    M[0] = mn[0]; M[1] = mn[1];

    // ---- P = exp2(S - m); pack to K16 B-frags ----
    h4 pB[4][2];
    #pragma unroll
    for (int mt = 0; mt < 4; ++mt)
      #pragma unroll
      for (int nt = 0; nt < 2; ++nt) {
        #pragma unroll
        for (int r = 0; r < 4; ++r)
          S[mt][nt][r] = fexp2(S[mt][nt][r] - mn[nt]);
        int2 tt;
        tt.x = __builtin_bit_cast(int, pk2(S[mt][nt][0], S[mt][nt][1]));
        tt.y = __builtin_bit_cast(int, pk2(S[mt][nt][2], S[mt][nt][3]));
        pB[mt][nt] = __builtin_bit_cast(h4, tt);
      }

    // ---- PV with one-keyblock-ahead V loads ----
    #pragma unroll
    for (int mt = 0; mt < 4; ++mt) {
      h8 vn0, vn1;
      if (mt == 0) { vn0 = *(const h8*)(vpl + 1024); vn1 = *(const h8*)(vpl + 1536); }
      if (mt == 1) { vn0 = *(const h8*)(vph);        vn1 = *(const h8*)(vph +  512); }
      if (mt == 2) { vn0 = *(const h8*)(vph + 1024); vn1 = *(const h8*)(vph + 1536); }
      const int4 vi0 = __builtin_bit_cast(int4, vc0);
      const int4 vi1 = __builtin_bit_cast(int4, vc1);
      int2 p01, p23, p45, p67;
      p01.x = vi0.x; p01.y = vi0.y;  p23.x = vi0.z; p23.y = vi0.w;
      p45.x = vi1.x; p45.y = vi1.y;  p67.x = vi1.z; p67.y = vi1.w;
      h4 va[4];
      va[0] = __builtin_bit_cast(h4, p01);
      va[1] = __builtin_bit_cast(h4, p23);
      va[2] = __builtin_bit_cast(h4, p45);
      va[3] = __builtin_bit_cast(h4, p67);
      #pragma unroll
      for (int ut = 0; ut < 4; ++ut)
        #pragma unroll
        for (int nt = 0; nt < 2; ++nt)
          O[ut][nt] = MFMA_K16(va[ut], pB[mt][nt], O[ut][nt]);
      #pragma unroll
      for (int nt = 0; nt < 2; ++nt)
        Ol[nt] = MFMA_K16(ones_a, pB[mt][nt], Ol[nt]);
      if (mt < 3) { vc0 = vn0; vc1 = vn1; }
    }

    vpl += 4096; vph += 4096;
  }

  // ---- epilogue ----
  const size_t rowg = (size_t)sp*BS + (size_t)b*SEQ + qbase;
  #pragma unroll
  for (int nt = 0; nt < 2; ++nt) {
    char* __restrict__ orow = (char*)(opart + (rowg + nt*16 + n)*UDIM);
    #pragma unroll
    for (int ut = 0; ut < 4; ++ut)
      #pragma unroll
      for (int p = 0; p < 2; ++p)
        *(unsigned*)(orow + (ut*16 + quad*4 + 2*p)*2) =
            __builtin_bit_cast(unsigned, pk2(O[ut][nt][2*p], O[ut][nt][2*p+1]));
    if (quad == 0) {
      Mp[rowg + nt*16 + n] = M[nt];        // log2 domain
      Lp[rowg + nt*16 + n] = Ol[nt][0];
    }
  }
}

// ---------------- Kernel C: merge key-split partials ----------------
__global__ __launch_bounds__(256) void merge_out(
    const _Float16* __restrict__ opart, const float* __restrict__ Mp,
    const float* __restrict__ Lp, float* __restrict__ out, int nsplit)
{
  const int tid = threadIdx.x;
  const int row = blockIdx.x*16 + (tid >> 4);
  const int u4  = (tid & 15) * 4;
  float M = -1e30f;
  for (int s = 0; s < nsplit; ++s) M = fmaxf(M, Mp[(size_t)s*BS + row]);
  f4 num = (f4){0.f,0.f,0.f,0.f};
  float den = 0.f;
  for (int s = 0; s < nsplit; ++s) {
    const float w = fexp2(Mp[(size_t)s*BS + row] - M);
    den += w * Lp[(size_t)s*BS + row];
    const h4 op = *(const h4*)(opart + ((size_t)s*BS + row)*UDIM + u4);
    #pragma unroll
    for (int i = 0; i < 4; ++i) num[i] += w * (float)op[i];
  }
  const float dinv = 1.f / den;
  *(f4*)(out + (size_t)row*UDIM + u4) = num * dinv;
}

extern "C" void kernel_launch(void* const* d_in, const int* in_sizes, int n_in,
                              void* d_out, int out_size, void* d_ws, size_t ws_size,
                              hipStream_t stream) {
  (void)in_sizes; (void)n_in; (void)out_size;
  const float* x  = (const float*)d_in[0];
  const float* Wq = (const float*)d_in[1];
  const float* bq = (const float*)d_in[2];
  const float* Wk = (const float*)d_in[3];
  const float* bk = (const float*)d_in[4];
  const float* Wv = (const float*)d_in[5];
  const float* bv = (const float*)d_in[6];
  float* out = (float*)d_out;

  char* ws = (char*)d_ws;
  const size_t fBytes = (size_t)BS * UDIM * 2;
  auto need = [](int nsp) {
    return (size_t)3*BS*UDIM*2 + (size_t)nsp*BS*4*2 + (size_t)nsp*BS*UDIM*2;
  };
  int nsplit;
  if      (ws_size >= need(8)) nsplit = 8;
  else if (ws_size >= need(4)) nsplit = 4;
  else if (ws_size >= need(2)) nsplit = 2;
  else                         nsplit = 1;

  _Float16* qf   = (_Float16*)(ws);
  _Float16* kswz = (_Float16*)(ws + fBytes);
  _Float16* vswz = (_Float16*)(ws + 2*fBytes);
  float* Mp      = (float*)(ws + 3*fBytes);
  float* Lp      = (float*)(ws + 3*fBytes + (size_t)nsplit*BS*4);
  _Float16* opart = (_Float16*)(ws + 3*fBytes + (size_t)nsplit*BS*8);

  proj_mfma<<<dim3(BS/64), 256, 0, stream>>>(x, Wq, bq, Wk, bk, Wv, bv, qf, kswz, vswz);
  flash_attn_t<<<dim3(SEQ/128, BATCH, nsplit), 256, 0, stream>>>(
      qf, kswz, vswz, opart, Mp, Lp, (SEQ/64)/nsplit);
  merge_out<<<dim3(BS/16), 256, 0, stream>>>(opart, Mp, Lp, out, nsplit);
}

// Round 13
// 112.962 us; speedup vs baseline: 1.4524x; 1.4524x over previous
//
#include <hip/hip_runtime.h>
#include <hip/hip_fp16.h>
#include <math.h>

#define SEQ   4096
#define DIM   128
#define UDIM  64
#define BATCH 4
#define BS    (BATCH*SEQ)

typedef _Float16 h8 __attribute__((ext_vector_type(8)));
typedef _Float16 h4 __attribute__((ext_vector_type(4)));
typedef _Float16 h2 __attribute__((ext_vector_type(2)));
typedef float    f4 __attribute__((ext_vector_type(4)));

#define MFMA_K32(a,b,c) __builtin_amdgcn_mfma_f32_16x16x32_f16((a),(b),(c),0,0,0)
#define MFMA_K16(a,b,c) __builtin_amdgcn_mfma_f32_16x16x16f16((a),(b),(c),0,0,0)

__device__ __forceinline__ h2 pk2(float a, float b) {
  return __builtin_bit_cast(h2, __builtin_amdgcn_cvt_pkrtz(a, b));
}
__device__ __forceinline__ float fexp2(float x) {
#if __has_builtin(__builtin_amdgcn_exp2f)
  return __builtin_amdgcn_exp2f(x);
#else
  return exp2f(x);
#endif
}

#define WT_STRIDE 272   // W^T row stride (136 halves): conflict-free b128
#define KB_STRIDE 144
#define L2E 1.44269504088896f

// Swizzled layouts, contiguous 8KB per 64-key tile (immediate-offset loads):
//  kswz: [kb][ks][lane] h8 : lane(quad,n) holds K[kb*16+n][ks*32+quad*8..+7]
//  vswz: [kb][pr][lane] h8 : low h4 = V^T[(2pr)*16+n][kb*16+quad*4..+3],
//                            high h4 = V^T[(2pr+1)*16+n][...]
// q is stored PRE-SCALED by log2(e) -> scores emerge in log2 domain.

// ---------------- Kernel A: FUSED qkv projection via MFMA ----------------
__global__ __launch_bounds__(256, 2) void proj_mfma(
    const float* __restrict__ x,
    const float* __restrict__ Wq, const float* __restrict__ bq,
    const float* __restrict__ Wk, const float* __restrict__ bk,
    const float* __restrict__ Wv, const float* __restrict__ bv,
    _Float16* __restrict__ qf, _Float16* __restrict__ kswz, _Float16* __restrict__ vswz)
{
  const int tid  = threadIdx.x;
  const int lane = tid & 63, wv = tid >> 6;
  const int n = lane & 15, quad = lane >> 4;
  const int r0 = blockIdx.x * 64;

  __shared__ __align__(16) char wlds[3][UDIM * WT_STRIDE];   // 52224 B
  __shared__ __align__(16) char kbnc[4 * 16 * KB_STRIDE];    //  9216 B

  #pragma unroll
  for (int p = 0; p < 3; ++p) {
    const float* __restrict__ W = (p == 0) ? Wq : ((p == 1) ? Wk : Wv);
    #pragma unroll
    for (int i = 0; i < 8; ++i) {
      const int idx = i*256 + tid;
      const int nn  = idx & 63;
      const int k4  = (idx >> 6) * 4;
      const float w0 = W[(k4+0)*UDIM + nn];
      const float w1 = W[(k4+1)*UDIM + nn];
      const float w2 = W[(k4+2)*UDIM + nn];
      const float w3 = W[(k4+3)*UDIM + nn];
      int2 wd;
      wd.x = __builtin_bit_cast(int, pk2(w0, w1));
      wd.y = __builtin_bit_cast(int, pk2(w2, w3));
      *(int2*)(wlds[p] + nn*WT_STRIDE + k4*2) = wd;
    }
  }

  const int row = r0 + wv*16 + n;
  h8 xa[4];
  #pragma unroll
  for (int ks = 0; ks < 4; ++ks) {
    const float* xp = x + (size_t)row*DIM + ks*32 + quad*8;
    const f4 a = *(const f4*)xp, b = *(const f4*)(xp + 4);
    int4 pkd;
    pkd.x = __builtin_bit_cast(int, pk2(a[0], a[1]));
    pkd.y = __builtin_bit_cast(int, pk2(a[2], a[3]));
    pkd.z = __builtin_bit_cast(int, pk2(b[0], b[1]));
    pkd.w = __builtin_bit_cast(int, pk2(b[2], b[3]));
    xa[ks] = __builtin_bit_cast(h8, pkd);
  }
  __syncthreads();

  const int b  = r0 / SEQ;
  const int kb = ((r0 % SEQ) >> 4) + wv;

  #pragma unroll
  for (int p = 0; p < 3; ++p) {
    const float* __restrict__ bias = (p == 0) ? bq : ((p == 1) ? bk : bv);
    f4 acc[4];
    #pragma unroll
    for (int nt = 0; nt < 4; ++nt) acc[nt] = (f4){0.f,0.f,0.f,0.f};
    #pragma unroll
    for (int ks = 0; ks < 4; ++ks)
      #pragma unroll
      for (int nt = 0; nt < 4; ++nt) {
        const h8 wf = *(const h8*)(wlds[p] + (nt*16 + n)*WT_STRIDE + (ks*32 + quad*8)*2);
        acc[nt] = MFMA_K32(xa[ks], wf, acc[nt]);
      }
    #pragma unroll
    for (int nt = 0; nt < 4; ++nt) {
      const float bb = bias[nt*16 + n];
      #pragma unroll
      for (int r = 0; r < 4; ++r) acc[nt][r] += bb;
    }

    if (p == 0) {
      #pragma unroll
      for (int nt = 0; nt < 4; ++nt)
        #pragma unroll
        for (int r = 0; r < 4; ++r) acc[nt][r] *= L2E;
      const int par = lane & 1;
      const unsigned sel = par ? 0x03020706u : 0x05040100u;
      #pragma unroll
      for (int nt = 0; nt < 4; ++nt)
        #pragma unroll
        for (int pp = 0; pp < 2; ++pp) {
          const int r = 2*pp;
          unsigned A  = __builtin_bit_cast(unsigned, pk2(acc[nt][r], acc[nt][r+1]));
          unsigned Bs = (unsigned)__builtin_amdgcn_mov_dpp((int)A, 0xB1, 0xF, 0xF, true);
          unsigned w  = __builtin_amdgcn_perm(Bs, A, sel);
          const int orow = r0 + wv*16 + 4*quad + r + par;
          const int ocol = nt*16 + n - par;
          *(unsigned*)((char*)qf + ((size_t)orow*UDIM + ocol)*2) = w;
        }
    } else if (p == 1) {
      char* base = kbnc + wv*(16*KB_STRIDE);
      #pragma unroll
      for (int nt = 0; nt < 4; ++nt)
        #pragma unroll
        for (int r = 0; r < 4; ++r)
          *(_Float16*)(base + (4*quad + r)*KB_STRIDE + (nt*16 + n)*2) =
              (_Float16)acc[nt][r];
      _Float16* kdst = kswz + (size_t)b*SEQ*UDIM;
      #pragma unroll
      for (int ks = 0; ks < 2; ++ks) {
        const h8 f = *(const h8*)(base + n*KB_STRIDE + ks*64 + quad*16);
        *(h8*)(kdst + ((size_t)(kb*2 + ks)*64 + lane)*8) = f;
      }
    } else {
      _Float16* vdst = vswz + (size_t)b*SEQ*UDIM;
      #pragma unroll
      for (int pr = 0; pr < 2; ++pr) {
        int4 t;
        t.x = __builtin_bit_cast(int, pk2(acc[2*pr][0],   acc[2*pr][1]));
        t.y = __builtin_bit_cast(int, pk2(acc[2*pr][2],   acc[2*pr][3]));
        t.z = __builtin_bit_cast(int, pk2(acc[2*pr+1][0], acc[2*pr+1][1]));
        t.w = __builtin_bit_cast(int, pk2(acc[2*pr+1][2], acc[2*pr+1][3]));
        *(int4*)(vdst + ((size_t)(kb*2 + pr)*64 + lane)*8) = t;
      }
    }
  }
}

// ---------------- Kernel B: barrier-free flash (R10 optimum) -------------
// K prefetched one tile ahead in place; V one keyblock ahead. (256,3):
// ~124-reg live set, 3 waves/SIMD, no spill — measured best configuration.
__global__ __launch_bounds__(256, 3) void flash_attn_t(
    const _Float16* __restrict__ qf, const _Float16* __restrict__ kswz,
    const _Float16* __restrict__ vswz,
    _Float16* __restrict__ opart, float* __restrict__ Mp, float* __restrict__ Lp,
    int nkt)
{
  const int qt = blockIdx.x, b = blockIdx.y, sp = blockIdx.z;
  const int tid = threadIdx.x;
  const int lane = tid & 63, wid = tid >> 6;
  const int n = lane & 15, quad = lane >> 4;
  const int qbase = qt*128 + wid*32;

  const _Float16* __restrict__ qb = qf + (size_t)b*SEQ*UDIM;
  const _Float16* kpl = kswz + (size_t)b*SEQ*UDIM + (size_t)sp*nkt*4096 + lane*8;
  const _Float16* kph = kpl + 2048;
  const _Float16* vpl = vswz + (size_t)b*SEQ*UDIM + (size_t)sp*nkt*4096 + lane*8;
  const _Float16* vph = vpl + 2048;

  h8 qB[2][2];
  #pragma unroll
  for (int nt = 0; nt < 2; ++nt)
    #pragma unroll
    for (int ks = 0; ks < 2; ++ks)
      qB[nt][ks] = *(const h8*)(qb + (size_t)(qbase + nt*16 + n)*UDIM + ks*32 + quad*8);

  f4 O[4][2], Ol[2];
  #pragma unroll
  for (int ut = 0; ut < 4; ++ut)
    #pragma unroll
    for (int nt = 0; nt < 2; ++nt) O[ut][nt] = (f4){0.f,0.f,0.f,0.f};
  Ol[0] = (f4){0.f,0.f,0.f,0.f};
  Ol[1] = (f4){0.f,0.f,0.f,0.f};

  float M[2] = {-1e30f, -1e30f};

  h4 ones_a;
  { const _Float16 o = (_Float16)1.0f;
    ones_a[0]=o; ones_a[1]=o; ones_a[2]=o; ones_a[3]=o; }

  // ---- prime K for tile 0 ----
  h8 ka[4][2];
  ka[0][0] = *(const h8*)(kpl);        ka[0][1] = *(const h8*)(kpl +  512);
  ka[1][0] = *(const h8*)(kpl + 1024); ka[1][1] = *(const h8*)(kpl + 1536);
  ka[2][0] = *(const h8*)(kph);        ka[2][1] = *(const h8*)(kph +  512);
  ka[3][0] = *(const h8*)(kph + 1024); ka[3][1] = *(const h8*)(kph + 1536);

  for (int t = 0; t < nkt; ++t) {
    // ---- V keyblock 0 loads: issue now, consumed after softmax ----
    h8 vc0 = *(const h8*)(vpl);
    h8 vc1 = *(const h8*)(vpl + 512);

    // ---- S^T = K·Q^T (log2 domain: q pre-scaled) ----
    f4 S[4][2];
    #pragma unroll
    for (int mt = 0; mt < 4; ++mt)
      #pragma unroll
      for (int nt = 0; nt < 2; ++nt) S[mt][nt] = (f4){0.f,0.f,0.f,0.f};
    #pragma unroll
    for (int ks = 0; ks < 2; ++ks)
      #pragma unroll
      for (int mt = 0; mt < 4; ++mt)
        #pragma unroll
        for (int nt = 0; nt < 2; ++nt)
          S[mt][nt] = MFMA_K32(ka[mt][ks], qB[nt][ks], S[mt][nt]);

    // ---- prefetch tile t+1's K in place (consumed next iter) ----
    if (t + 1 < nkt) {
      kpl += 4096; kph += 4096;
      ka[0][0] = *(const h8*)(kpl);        ka[0][1] = *(const h8*)(kpl +  512);
      ka[1][0] = *(const h8*)(kpl + 1024); ka[1][1] = *(const h8*)(kpl + 1536);
      ka[2][0] = *(const h8*)(kph);        ka[2][1] = *(const h8*)(kph +  512);
      ka[3][0] = *(const h8*)(kph + 1024); ka[3][1] = *(const h8*)(kph + 1536);
    }

    // ---- row max: tree + 2 shuffles ----
    float mn[2];
    #pragma unroll
    for (int nt = 0; nt < 2; ++nt) {
      float m0 = fmaxf(fmaxf(S[0][nt][0], S[0][nt][1]), fmaxf(S[0][nt][2], S[0][nt][3]));
      float m1 = fmaxf(fmaxf(S[1][nt][0], S[1][nt][1]), fmaxf(S[1][nt][2], S[1][nt][3]));
      float m2 = fmaxf(fmaxf(S[2][nt][0], S[2][nt][1]), fmaxf(S[2][nt][2], S[2][nt][3]));
      float m3 = fmaxf(fmaxf(S[3][nt][0], S[3][nt][1]), fmaxf(S[3][nt][2], S[3][nt][3]));
      float rm = fmaxf(fmaxf(m0, m1), fmaxf(m2, m3));
      rm = fmaxf(rm, __shfl_xor(rm, 16));
      rm = fmaxf(rm, __shfl_xor(rm, 32));
      mn[nt] = fmaxf(M[nt], rm);
    }

    // ---- rescale O only if some lane's max moved ----
    const bool nochange = (mn[0] == M[0]) && (mn[1] == M[1]);
    if (!__all(nochange)) {
      #pragma unroll
      for (int nt = 0; nt < 2; ++nt) {
        const float alpha = fexp2(M[nt] - mn[nt]);
        #pragma unroll
        for (int ut = 0; ut < 4; ++ut)
          #pragma unroll
          for (int r = 0; r < 4; ++r) O[ut][nt][r] *= alpha;
        #pragma unroll
        for (int r = 0; r < 4; ++r) Ol[nt][r] *= alpha;
      }
    }
    M[0] = mn[0]; M[1] = mn[1];

    // ---- P = exp2(S - m); pack to K16 B-frags ----
    h4 pB[4][2];
    #pragma unroll
    for (int mt = 0; mt < 4; ++mt)
      #pragma unroll
      for (int nt = 0; nt < 2; ++nt) {
        #pragma unroll
        for (int r = 0; r < 4; ++r)
          S[mt][nt][r] = fexp2(S[mt][nt][r] - mn[nt]);
        int2 tt;
        tt.x = __builtin_bit_cast(int, pk2(S[mt][nt][0], S[mt][nt][1]));
        tt.y = __builtin_bit_cast(int, pk2(S[mt][nt][2], S[mt][nt][3]));
        pB[mt][nt] = __builtin_bit_cast(h4, tt);
      }

    // ---- PV with one-keyblock-ahead V loads ----
    #pragma unroll
    for (int mt = 0; mt < 4; ++mt) {
      h8 vn0, vn1;
      if (mt == 0) { vn0 = *(const h8*)(vpl + 1024); vn1 = *(const h8*)(vpl + 1536); }
      if (mt == 1) { vn0 = *(const h8*)(vph);        vn1 = *(const h8*)(vph +  512); }
      if (mt == 2) { vn0 = *(const h8*)(vph + 1024); vn1 = *(const h8*)(vph + 1536); }
      const int4 vi0 = __builtin_bit_cast(int4, vc0);
      const int4 vi1 = __builtin_bit_cast(int4, vc1);
      int2 p01, p23, p45, p67;
      p01.x = vi0.x; p01.y = vi0.y;  p23.x = vi0.z; p23.y = vi0.w;
      p45.x = vi1.x; p45.y = vi1.y;  p67.x = vi1.z; p67.y = vi1.w;
      h4 va[4];
      va[0] = __builtin_bit_cast(h4, p01);
      va[1] = __builtin_bit_cast(h4, p23);
      va[2] = __builtin_bit_cast(h4, p45);
      va[3] = __builtin_bit_cast(h4, p67);
      #pragma unroll
      for (int ut = 0; ut < 4; ++ut)
        #pragma unroll
        for (int nt = 0; nt < 2; ++nt)
          O[ut][nt] = MFMA_K16(va[ut], pB[mt][nt], O[ut][nt]);
      #pragma unroll
      for (int nt = 0; nt < 2; ++nt)
        Ol[nt] = MFMA_K16(ones_a, pB[mt][nt], Ol[nt]);
      if (mt < 3) { vc0 = vn0; vc1 = vn1; }
    }

    vpl += 4096; vph += 4096;
  }

  // ---- epilogue ----
  const size_t rowg = (size_t)sp*BS + (size_t)b*SEQ + qbase;
  #pragma unroll
  for (int nt = 0; nt < 2; ++nt) {
    char* __restrict__ orow = (char*)(opart + (rowg + nt*16 + n)*UDIM);
    #pragma unroll
    for (int ut = 0; ut < 4; ++ut)
      #pragma unroll
      for (int p = 0; p < 2; ++p)
        *(unsigned*)(orow + (ut*16 + quad*4 + 2*p)*2) =
            __builtin_bit_cast(unsigned, pk2(O[ut][nt][2*p], O[ut][nt][2*p+1]));
    if (quad == 0) {
      Mp[rowg + nt*16 + n] = M[nt];        // log2 domain
      Lp[rowg + nt*16 + n] = Ol[nt][0];
    }
  }
}

// ---------------- Kernel C: merge key-split partials ----------------
__global__ __launch_bounds__(256) void merge_out(
    const _Float16* __restrict__ opart, const float* __restrict__ Mp,
    const float* __restrict__ Lp, float* __restrict__ out, int nsplit)
{
  const int tid = threadIdx.x;
  const int row = blockIdx.x*16 + (tid >> 4);
  const int u4  = (tid & 15) * 4;
  float M = -1e30f;
  for (int s = 0; s < nsplit; ++s) M = fmaxf(M, Mp[(size_t)s*BS + row]);
  f4 num = (f4){0.f,0.f,0.f,0.f};
  float den = 0.f;
  for (int s = 0; s < nsplit; ++s) {
    const float w = fexp2(Mp[(size_t)s*BS + row] - M);
    den += w * Lp[(size_t)s*BS + row];
    const h4 op = *(const h4*)(opart + ((size_t)s*BS + row)*UDIM + u4);
    #pragma unroll
    for (int i = 0; i < 4; ++i) num[i] += w * (float)op[i];
  }
  const float dinv = 1.f / den;
  *(f4*)(out + (size_t)row*UDIM + u4) = num * dinv;
}

extern "C" void kernel_launch(void* const* d_in, const int* in_sizes, int n_in,
                              void* d_out, int out_size, void* d_ws, size_t ws_size,
                              hipStream_t stream) {
  (void)in_sizes; (void)n_in; (void)out_size;
  const float* x  = (const float*)d_in[0];
  const float* Wq = (const float*)d_in[1];
  const float* bq = (const float*)d_in[2];
  const float* Wk = (const float*)d_in[3];
  const float* bk = (const float*)d_in[4];
  const float* Wv = (const float*)d_in[5];
  const float* bv = (const float*)d_in[6];
  float* out = (float*)d_out;

  char* ws = (char*)d_ws;
  const size_t fBytes = (size_t)BS * UDIM * 2;
  auto need = [](int nsp) {
    return (size_t)3*BS*UDIM*2 + (size_t)nsp*BS*4*2 + (size_t)nsp*BS*UDIM*2;
  };
  int nsplit;
  if      (ws_size >= need(8)) nsplit = 8;
  else if (ws_size >= need(4)) nsplit = 4;
  else if (ws_size >= need(2)) nsplit = 2;
  else                         nsplit = 1;

  _Float16* qf   = (_Float16*)(ws);
  _Float16* kswz = (_Float16*)(ws + fBytes);
  _Float16* vswz = (_Float16*)(ws + 2*fBytes);
  float* Mp      = (float*)(ws + 3*fBytes);
  float* Lp      = (float*)(ws + 3*fBytes + (size_t)nsplit*BS*4);
  _Float16* opart = (_Float16*)(ws + 3*fBytes + (size_t)nsplit*BS*8);

  proj_mfma<<<dim3(BS/64), 256, 0, stream>>>(x, Wq, bq, Wk, bk, Wv, bv, qf, kswz, vswz);
  flash_attn_t<<<dim3(SEQ/128, BATCH, nsplit), 256, 0, stream>>>(
      qf, kswz, vswz, opart, Mp, Lp, (SEQ/64)/nsplit);
  merge_out<<<dim3(BS/16), 256, 0, stream>>>(opart, Mp, Lp, out, nsplit);
}

// Round 14
// 109.611 us; speedup vs baseline: 1.4969x; 1.0306x over previous
//
#include <hip/hip_runtime.h>
#include <hip/hip_fp16.h>
#include <math.h>

#define SEQ   4096
#define DIM   128
#define UDIM  64
#define BATCH 4
#define BS    (BATCH*SEQ)
#define NT    (SEQ/64)   // 64 key tiles
#define NSPLIT 6         // 768 blocks = 3072 waves = exactly one resident pass

typedef _Float16 h8 __attribute__((ext_vector_type(8)));
typedef _Float16 h4 __attribute__((ext_vector_type(4)));
typedef _Float16 h2 __attribute__((ext_vector_type(2)));
typedef float    f4 __attribute__((ext_vector_type(4)));

#define MFMA_K32(a,b,c) __builtin_amdgcn_mfma_f32_16x16x32_f16((a),(b),(c),0,0,0)
#define MFMA_K16(a,b,c) __builtin_amdgcn_mfma_f32_16x16x16f16((a),(b),(c),0,0,0)

__device__ __forceinline__ h2 pk2(float a, float b) {
  return __builtin_bit_cast(h2, __builtin_amdgcn_cvt_pkrtz(a, b));
}
__device__ __forceinline__ float fexp2(float x) {
#if __has_builtin(__builtin_amdgcn_exp2f)
  return __builtin_amdgcn_exp2f(x);
#else
  return exp2f(x);
#endif
}

#define WT_STRIDE 272   // W^T row stride (136 halves): conflict-free b128
#define KB_STRIDE 144
#define L2E 1.44269504088896f

// Swizzled layouts, contiguous 8KB per 64-key tile (immediate-offset loads):
//  kswz: [kb][ks][lane] h8 : lane(quad,n) holds K[kb*16+n][ks*32+quad*8..+7]
//  vswz: [kb][pr][lane] h8 : low h4 = V^T[(2pr)*16+n][kb*16+quad*4..+3],
//                            high h4 = V^T[(2pr+1)*16+n][...]
// q is stored PRE-SCALED by log2(e) -> scores emerge in log2 domain.

// ---------------- Kernel A: FUSED qkv projection via MFMA ----------------
__global__ __launch_bounds__(256, 2) void proj_mfma(
    const float* __restrict__ x,
    const float* __restrict__ Wq, const float* __restrict__ bq,
    const float* __restrict__ Wk, const float* __restrict__ bk,
    const float* __restrict__ Wv, const float* __restrict__ bv,
    _Float16* __restrict__ qf, _Float16* __restrict__ kswz, _Float16* __restrict__ vswz)
{
  const int tid  = threadIdx.x;
  const int lane = tid & 63, wv = tid >> 6;
  const int n = lane & 15, quad = lane >> 4;
  const int r0 = blockIdx.x * 64;

  __shared__ __align__(16) char wlds[3][UDIM * WT_STRIDE];   // 52224 B
  __shared__ __align__(16) char kbnc[4 * 16 * KB_STRIDE];    //  9216 B

  #pragma unroll
  for (int p = 0; p < 3; ++p) {
    const float* __restrict__ W = (p == 0) ? Wq : ((p == 1) ? Wk : Wv);
    #pragma unroll
    for (int i = 0; i < 8; ++i) {
      const int idx = i*256 + tid;
      const int nn  = idx & 63;
      const int k4  = (idx >> 6) * 4;
      const float w0 = W[(k4+0)*UDIM + nn];
      const float w1 = W[(k4+1)*UDIM + nn];
      const float w2 = W[(k4+2)*UDIM + nn];
      const float w3 = W[(k4+3)*UDIM + nn];
      int2 wd;
      wd.x = __builtin_bit_cast(int, pk2(w0, w1));
      wd.y = __builtin_bit_cast(int, pk2(w2, w3));
      *(int2*)(wlds[p] + nn*WT_STRIDE + k4*2) = wd;
    }
  }

  const int row = r0 + wv*16 + n;
  h8 xa[4];
  #pragma unroll
  for (int ks = 0; ks < 4; ++ks) {
    const float* xp = x + (size_t)row*DIM + ks*32 + quad*8;
    const f4 a = *(const f4*)xp, b = *(const f4*)(xp + 4);
    int4 pkd;
    pkd.x = __builtin_bit_cast(int, pk2(a[0], a[1]));
    pkd.y = __builtin_bit_cast(int, pk2(a[2], a[3]));
    pkd.z = __builtin_bit_cast(int, pk2(b[0], b[1]));
    pkd.w = __builtin_bit_cast(int, pk2(b[2], b[3]));
    xa[ks] = __builtin_bit_cast(h8, pkd);
  }
  __syncthreads();

  const int b  = r0 / SEQ;
  const int kb = ((r0 % SEQ) >> 4) + wv;

  #pragma unroll
  for (int p = 0; p < 3; ++p) {
    const float* __restrict__ bias = (p == 0) ? bq : ((p == 1) ? bk : bv);
    f4 acc[4];
    #pragma unroll
    for (int nt = 0; nt < 4; ++nt) acc[nt] = (f4){0.f,0.f,0.f,0.f};
    #pragma unroll
    for (int ks = 0; ks < 4; ++ks)
      #pragma unroll
      for (int nt = 0; nt < 4; ++nt) {
        const h8 wf = *(const h8*)(wlds[p] + (nt*16 + n)*WT_STRIDE + (ks*32 + quad*8)*2);
        acc[nt] = MFMA_K32(xa[ks], wf, acc[nt]);
      }
    #pragma unroll
    for (int nt = 0; nt < 4; ++nt) {
      const float bb = bias[nt*16 + n];
      #pragma unroll
      for (int r = 0; r < 4; ++r) acc[nt][r] += bb;
    }

    if (p == 0) {
      #pragma unroll
      for (int nt = 0; nt < 4; ++nt)
        #pragma unroll
        for (int r = 0; r < 4; ++r) acc[nt][r] *= L2E;
      const int par = lane & 1;
      const unsigned sel = par ? 0x03020706u : 0x05040100u;
      #pragma unroll
      for (int nt = 0; nt < 4; ++nt)
        #pragma unroll
        for (int pp = 0; pp < 2; ++pp) {
          const int r = 2*pp;
          unsigned A  = __builtin_bit_cast(unsigned, pk2(acc[nt][r], acc[nt][r+1]));
          unsigned Bs = (unsigned)__builtin_amdgcn_mov_dpp((int)A, 0xB1, 0xF, 0xF, true);
          unsigned w  = __builtin_amdgcn_perm(Bs, A, sel);
          const int orow = r0 + wv*16 + 4*quad + r + par;
          const int ocol = nt*16 + n - par;
          *(unsigned*)((char*)qf + ((size_t)orow*UDIM + ocol)*2) = w;
        }
    } else if (p == 1) {
      char* base = kbnc + wv*(16*KB_STRIDE);
      #pragma unroll
      for (int nt = 0; nt < 4; ++nt)
        #pragma unroll
        for (int r = 0; r < 4; ++r)
          *(_Float16*)(base + (4*quad + r)*KB_STRIDE + (nt*16 + n)*2) =
              (_Float16)acc[nt][r];
      _Float16* kdst = kswz + (size_t)b*SEQ*UDIM;
      #pragma unroll
      for (int ks = 0; ks < 2; ++ks) {
        const h8 f = *(const h8*)(base + n*KB_STRIDE + ks*64 + quad*16);
        *(h8*)(kdst + ((size_t)(kb*2 + ks)*64 + lane)*8) = f;
      }
    } else {
      _Float16* vdst = vswz + (size_t)b*SEQ*UDIM;
      #pragma unroll
      for (int pr = 0; pr < 2; ++pr) {
        int4 t;
        t.x = __builtin_bit_cast(int, pk2(acc[2*pr][0],   acc[2*pr][1]));
        t.y = __builtin_bit_cast(int, pk2(acc[2*pr][2],   acc[2*pr][3]));
        t.z = __builtin_bit_cast(int, pk2(acc[2*pr+1][0], acc[2*pr+1][1]));
        t.w = __builtin_bit_cast(int, pk2(acc[2*pr+1][2], acc[2*pr+1][3]));
        *(int4*)(vdst + ((size_t)(kb*2 + pr)*64 + lane)*8) = t;
      }
    }
  }
}

// ---------------- Kernel B: barrier-free flash (R10 pipeline, packed grid)
// nsplit=6 with rounded tile boundaries: 3072 waves = exactly the number of
// resident wave slots at 3 waves/SIMD -> one clean pass, no ragged tail.
__global__ __launch_bounds__(256, 3) void flash_attn_t(
    const _Float16* __restrict__ qf, const _Float16* __restrict__ kswz,
    const _Float16* __restrict__ vswz,
    _Float16* __restrict__ opart, float* __restrict__ Mp, float* __restrict__ Lp)
{
  const int qt = blockIdx.x, b = blockIdx.y, sp = blockIdx.z;
  const int ns = gridDim.z;
  const int kt0 = (sp * NT) / ns;
  const int kt1 = ((sp + 1) * NT) / ns;
  const int tid = threadIdx.x;
  const int lane = tid & 63, wid = tid >> 6;
  const int n = lane & 15, quad = lane >> 4;
  const int qbase = qt*128 + wid*32;

  const _Float16* __restrict__ qb = qf + (size_t)b*SEQ*UDIM;
  const _Float16* kpl = kswz + (size_t)b*SEQ*UDIM + (size_t)kt0*4096 + lane*8;
  const _Float16* kph = kpl + 2048;
  const _Float16* vpl = vswz + (size_t)b*SEQ*UDIM + (size_t)kt0*4096 + lane*8;
  const _Float16* vph = vpl + 2048;

  h8 qB[2][2];
  #pragma unroll
  for (int nt = 0; nt < 2; ++nt)
    #pragma unroll
    for (int ks = 0; ks < 2; ++ks)
      qB[nt][ks] = *(const h8*)(qb + (size_t)(qbase + nt*16 + n)*UDIM + ks*32 + quad*8);

  f4 O[4][2], Ol[2];
  #pragma unroll
  for (int ut = 0; ut < 4; ++ut)
    #pragma unroll
    for (int nt = 0; nt < 2; ++nt) O[ut][nt] = (f4){0.f,0.f,0.f,0.f};
  Ol[0] = (f4){0.f,0.f,0.f,0.f};
  Ol[1] = (f4){0.f,0.f,0.f,0.f};

  float M[2] = {-1e30f, -1e30f};

  h4 ones_a;
  { const _Float16 o = (_Float16)1.0f;
    ones_a[0]=o; ones_a[1]=o; ones_a[2]=o; ones_a[3]=o; }

  // ---- prime K for first tile ----
  h8 ka[4][2];
  ka[0][0] = *(const h8*)(kpl);        ka[0][1] = *(const h8*)(kpl +  512);
  ka[1][0] = *(const h8*)(kpl + 1024); ka[1][1] = *(const h8*)(kpl + 1536);
  ka[2][0] = *(const h8*)(kph);        ka[2][1] = *(const h8*)(kph +  512);
  ka[3][0] = *(const h8*)(kph + 1024); ka[3][1] = *(const h8*)(kph + 1536);

  for (int t = kt0; t < kt1; ++t) {
    // ---- V keyblock 0 loads: issue now, consumed after softmax ----
    h8 vc0 = *(const h8*)(vpl);
    h8 vc1 = *(const h8*)(vpl + 512);

    // ---- S^T = K·Q^T (log2 domain: q pre-scaled) ----
    f4 S[4][2];
    #pragma unroll
    for (int mt = 0; mt < 4; ++mt)
      #pragma unroll
      for (int nt = 0; nt < 2; ++nt) S[mt][nt] = (f4){0.f,0.f,0.f,0.f};
    #pragma unroll
    for (int ks = 0; ks < 2; ++ks)
      #pragma unroll
      for (int mt = 0; mt < 4; ++mt)
        #pragma unroll
        for (int nt = 0; nt < 2; ++nt)
          S[mt][nt] = MFMA_K32(ka[mt][ks], qB[nt][ks], S[mt][nt]);

    // ---- prefetch next tile's K in place (consumed next iter) ----
    if (t + 1 < kt1) {
      kpl += 4096; kph += 4096;
      ka[0][0] = *(const h8*)(kpl);        ka[0][1] = *(const h8*)(kpl +  512);
      ka[1][0] = *(const h8*)(kpl + 1024); ka[1][1] = *(const h8*)(kpl + 1536);
      ka[2][0] = *(const h8*)(kph);        ka[2][1] = *(const h8*)(kph +  512);
      ka[3][0] = *(const h8*)(kph + 1024); ka[3][1] = *(const h8*)(kph + 1536);
    }

    // ---- row max: tree + 2 shuffles ----
    float mn[2];
    #pragma unroll
    for (int nt = 0; nt < 2; ++nt) {
      float m0 = fmaxf(fmaxf(S[0][nt][0], S[0][nt][1]), fmaxf(S[0][nt][2], S[0][nt][3]));
      float m1 = fmaxf(fmaxf(S[1][nt][0], S[1][nt][1]), fmaxf(S[1][nt][2], S[1][nt][3]));
      float m2 = fmaxf(fmaxf(S[2][nt][0], S[2][nt][1]), fmaxf(S[2][nt][2], S[2][nt][3]));
      float m3 = fmaxf(fmaxf(S[3][nt][0], S[3][nt][1]), fmaxf(S[3][nt][2], S[3][nt][3]));
      float rm = fmaxf(fmaxf(m0, m1), fmaxf(m2, m3));
      rm = fmaxf(rm, __shfl_xor(rm, 16));
      rm = fmaxf(rm, __shfl_xor(rm, 32));
      mn[nt] = fmaxf(M[nt], rm);
    }

    // ---- rescale O only if some lane's max moved ----
    const bool nochange = (mn[0] == M[0]) && (mn[1] == M[1]);
    if (!__all(nochange)) {
      #pragma unroll
      for (int nt = 0; nt < 2; ++nt) {
        const float alpha = fexp2(M[nt] - mn[nt]);
        #pragma unroll
        for (int ut = 0; ut < 4; ++ut)
          #pragma unroll
          for (int r = 0; r < 4; ++r) O[ut][nt][r] *= alpha;
        #pragma unroll
        for (int r = 0; r < 4; ++r) Ol[nt][r] *= alpha;
      }
    }
    M[0] = mn[0]; M[1] = mn[1];

    // ---- P = exp2(S - m); pack to K16 B-frags ----
    h4 pB[4][2];
    #pragma unroll
    for (int mt = 0; mt < 4; ++mt)
      #pragma unroll
      for (int nt = 0; nt < 2; ++nt) {
        #pragma unroll
        for (int r = 0; r < 4; ++r)
          S[mt][nt][r] = fexp2(S[mt][nt][r] - mn[nt]);
        int2 tt;
        tt.x = __builtin_bit_cast(int, pk2(S[mt][nt][0], S[mt][nt][1]));
        tt.y = __builtin_bit_cast(int, pk2(S[mt][nt][2], S[mt][nt][3]));
        pB[mt][nt] = __builtin_bit_cast(h4, tt);
      }

    // ---- PV with one-keyblock-ahead V loads ----
    #pragma unroll
    for (int mt = 0; mt < 4; ++mt) {
      h8 vn0, vn1;
      if (mt == 0) { vn0 = *(const h8*)(vpl + 1024); vn1 = *(const h8*)(vpl + 1536); }
      if (mt == 1) { vn0 = *(const h8*)(vph);        vn1 = *(const h8*)(vph +  512); }
      if (mt == 2) { vn0 = *(const h8*)(vph + 1024); vn1 = *(const h8*)(vph + 1536); }
      const int4 vi0 = __builtin_bit_cast(int4, vc0);
      const int4 vi1 = __builtin_bit_cast(int4, vc1);
      int2 p01, p23, p45, p67;
      p01.x = vi0.x; p01.y = vi0.y;  p23.x = vi0.z; p23.y = vi0.w;
      p45.x = vi1.x; p45.y = vi1.y;  p67.x = vi1.z; p67.y = vi1.w;
      h4 va[4];
      va[0] = __builtin_bit_cast(h4, p01);
      va[1] = __builtin_bit_cast(h4, p23);
      va[2] = __builtin_bit_cast(h4, p45);
      va[3] = __builtin_bit_cast(h4, p67);
      #pragma unroll
      for (int ut = 0; ut < 4; ++ut)
        #pragma unroll
        for (int nt = 0; nt < 2; ++nt)
          O[ut][nt] = MFMA_K16(va[ut], pB[mt][nt], O[ut][nt]);
      #pragma unroll
      for (int nt = 0; nt < 2; ++nt)
        Ol[nt] = MFMA_K16(ones_a, pB[mt][nt], Ol[nt]);
      if (mt < 3) { vc0 = vn0; vc1 = vn1; }
    }

    vpl += 4096; vph += 4096;
  }

  // ---- epilogue ----
  const size_t rowg = (size_t)sp*BS + (size_t)b*SEQ + qbase;
  #pragma unroll
  for (int nt = 0; nt < 2; ++nt) {
    char* __restrict__ orow = (char*)(opart + (rowg + nt*16 + n)*UDIM);
    #pragma unroll
    for (int ut = 0; ut < 4; ++ut)
      #pragma unroll
      for (int p = 0; p < 2; ++p)
        *(unsigned*)(orow + (ut*16 + quad*4 + 2*p)*2) =
            __builtin_bit_cast(unsigned, pk2(O[ut][nt][2*p], O[ut][nt][2*p+1]));
    if (quad == 0) {
      Mp[rowg + nt*16 + n] = M[nt];        // log2 domain
      Lp[rowg + nt*16 + n] = Ol[nt][0];
    }
  }
}

// ---------------- Kernel C: merge key-split partials ----------------
__global__ __launch_bounds__(256) void merge_out(
    const _Float16* __restrict__ opart, const float* __restrict__ Mp,
    const float* __restrict__ Lp, float* __restrict__ out, int nsplit)
{
  const int tid = threadIdx.x;
  const int row = blockIdx.x*16 + (tid >> 4);
  const int u4  = (tid & 15) * 4;
  float M = -1e30f;
  for (int s = 0; s < nsplit; ++s) M = fmaxf(M, Mp[(size_t)s*BS + row]);
  f4 num = (f4){0.f,0.f,0.f,0.f};
  float den = 0.f;
  for (int s = 0; s < nsplit; ++s) {
    const float w = fexp2(Mp[(size_t)s*BS + row] - M);
    den += w * Lp[(size_t)s*BS + row];
    const h4 op = *(const h4*)(opart + ((size_t)s*BS + row)*UDIM + u4);
    #pragma unroll
    for (int i = 0; i < 4; ++i) num[i] += w * (float)op[i];
  }
  const float dinv = 1.f / den;
  *(f4*)(out + (size_t)row*UDIM + u4) = num * dinv;
}

extern "C" void kernel_launch(void* const* d_in, const int* in_sizes, int n_in,
                              void* d_out, int out_size, void* d_ws, size_t ws_size,
                              hipStream_t stream) {
  (void)in_sizes; (void)n_in; (void)out_size;
  const float* x  = (const float*)d_in[0];
  const float* Wq = (const float*)d_in[1];
  const float* bq = (const float*)d_in[2];
  const float* Wk = (const float*)d_in[3];
  const float* bk = (const float*)d_in[4];
  const float* Wv = (const float*)d_in[5];
  const float* bv = (const float*)d_in[6];
  float* out = (float*)d_out;

  char* ws = (char*)d_ws;
  const size_t fBytes = (size_t)BS * UDIM * 2;
  auto need = [](int nsp) {
    return (size_t)3*BS*UDIM*2 + (size_t)nsp*BS*4*2 + (size_t)nsp*BS*UDIM*2;
  };
  int nsplit;
  if      (ws_size >= need(NSPLIT)) nsplit = NSPLIT;
  else if (ws_size >= need(4))      nsplit = 4;
  else if (ws_size >= need(2))      nsplit = 2;
  else                              nsplit = 1;

  _Float16* qf   = (_Float16*)(ws);
  _Float16* kswz = (_Float16*)(ws + fBytes);
  _Float16* vswz = (_Float16*)(ws + 2*fBytes);
  float* Mp      = (float*)(ws + 3*fBytes);
  float* Lp      = (float*)(ws + 3*fBytes + (size_t)nsplit*BS*4);
  _Float16* opart = (_Float16*)(ws + 3*fBytes + (size_t)nsplit*BS*8);

  proj_mfma<<<dim3(BS/64), 256, 0, stream>>>(x, Wq, bq, Wk, bk, Wv, bv, qf, kswz, vswz);
  flash_attn_t<<<dim3(SEQ/128, BATCH, nsplit), 256, 0, stream>>>(
      qf, kswz, vswz, opart, Mp, Lp);
  merge_out<<<dim3(BS/16), 256, 0, stream>>>(opart, Mp, Lp, out, nsplit);
}